// Round 8
// baseline (301.390 us; speedup 1.0000x reference)
//
#include <hip/hip_runtime.h>

// HyperNet fused forward, v11.
//   logits = h1h2 @ fused(+bias row), fused = [enc_w2;pol_w3;pol_b3]@comb_w (+comb_b)
//
// R7 triangulation: v4 (LDS-broadcast h) / v9 (s_load h) / v10 (32-row s_load) all
//   re-read the full 397KB fused from L2 per block and all land 75-85us -> the fused
//   L2 re-read is the invariant limit. v11 stages the block's fused j-slice into LDS
//   ONCE (49.7KB, 3 blocks/CU) and reads it per-lane (ds_read_b64, 1 b64 per 32
//   FMA-cyc = LDS pipe ~50% of VALU -- per-lane, NOT the v4 broadcast pattern).
//   h rows assigned per-WAVE (readfirstlane(t>>6)) -> provably uniform -> s_load in
//   4-row chunks (v9-proven granularity). j-split x8; logprob via atomicAdd onto
//   constants initialized by stage1's new fill blocks.

#define N_CLIENTS 16384
#define P 1024
#define IN_DIM 512
#define SPAD 36   // LDS row stride for A tiles

#define FMA4(acc, a, w0, w1, w2, w3)                                  \
  acc.x = fmaf(a.x, w0.x, acc.x); acc.y = fmaf(a.x, w0.y, acc.y);     \
  acc.z = fmaf(a.x, w0.z, acc.z); acc.w = fmaf(a.x, w0.w, acc.w);     \
  acc.x = fmaf(a.y, w1.x, acc.x); acc.y = fmaf(a.y, w1.y, acc.y);     \
  acc.z = fmaf(a.y, w1.z, acc.z); acc.w = fmaf(a.y, w1.w, acc.w);     \
  acc.x = fmaf(a.z, w2.x, acc.x); acc.y = fmaf(a.z, w2.y, acc.y);     \
  acc.z = fmaf(a.z, w2.z, acc.z); acc.w = fmaf(a.z, w2.w, acc.w);     \
  acc.x = fmaf(a.w, w3.x, acc.x); acc.y = fmaf(a.w, w3.y, acc.y);     \
  acc.z = fmaf(a.w, w3.z, acc.z); acc.w = fmaf(a.w, w3.w, acc.w);

// ---------------------------------------------------------------------------
// stage1 (v4-proven): [0,512) h1 | [512,768) h2 | [768,1600) precompute
//                     [1600,1664) logprob/entropy constant fill
// ---------------------------------------------------------------------------
__global__ __launch_bounds__(256) void stage1(
    const float* __restrict__ encoding,  // [N][512]
    const float* __restrict__ mean,      // [N][1024]
    const float* __restrict__ enc_w1,    // [512][64]
    const float* __restrict__ pol_w1,    // [1024][32]
    const float* __restrict__ pol_b1,    // [32]
    const float* __restrict__ pol_w2,    // [32][32]
    const float* __restrict__ pol_b2,    // [32]
    const float* __restrict__ enc_w2,    // [64][1024]
    const float* __restrict__ pol_w3,    // [32][1024]
    const float* __restrict__ pol_b3,    // [1024]
    const float* __restrict__ comb_w,    // [2048][1024]
    const float* __restrict__ comb_b,    // [1024]
    float* __restrict__ h1h2,            // [N][96]
    float* __restrict__ fused,           // [97][1024] (pre-zeroed)
    float* __restrict__ out_logprob,     // [N]
    float* __restrict__ out_entropy)     // [N]
{
    __shared__ __attribute__((aligned(16))) float smem[64 * SPAD + 32 * 32]; // 13.3 KB
    const int t = threadIdx.x;
    const int bid = blockIdx.x;

    if (bid < 512) {
        // ---- h1: 32 rows x 64 cols, K=512 in 16 tiles of 32, reg-prefetch staging.
        float* sA = smem;                 // [32][SPAD]
        float* sW = smem + 32 * SPAD;     // [32][64]
        const long r0 = (long)bid * 32;
        const int tr = t & 15, rr = t >> 4;
        const int c0 = tr * 4;
        const int arow = t >> 3, aseg = t & 7;
        const float* aSrc = encoding + (r0 + arow) * IN_DIM + aseg * 4;

        float4 aR  = *(const float4*)(aSrc);
        float4 wR0 = *(const float4*)(enc_w1 + t * 4);
        float4 wR1 = *(const float4*)(enc_w1 + (256 + t) * 4);
        float4 acc0 = {0.f,0.f,0.f,0.f}, acc1 = {0.f,0.f,0.f,0.f};

        for (int kt = 0; kt < 16; ++kt) {
            __syncthreads();
            *(float4*)(sA + arow * SPAD + aseg * 4) = aR;
            *(float4*)(sW + t * 4) = wR0;
            *(float4*)(sW + (256 + t) * 4) = wR1;
            __syncthreads();
            if (kt < 15) {
                aR  = *(const float4*)(aSrc + (kt + 1) * 32);
                wR0 = *(const float4*)(enc_w1 + (kt + 1) * 2048 + t * 4);
                wR1 = *(const float4*)(enc_w1 + (kt + 1) * 2048 + (256 + t) * 4);
            }
            #pragma unroll
            for (int k4 = 0; k4 < 8; ++k4) {
                const float4 a0 = *(const float4*)(sA + (rr * 2 + 0) * SPAD + k4 * 4);
                const float4 a1 = *(const float4*)(sA + (rr * 2 + 1) * SPAD + k4 * 4);
                const float4 w0 = *(const float4*)(sW + (k4 * 4 + 0) * 64 + c0);
                const float4 w1 = *(const float4*)(sW + (k4 * 4 + 1) * 64 + c0);
                const float4 w2 = *(const float4*)(sW + (k4 * 4 + 2) * 64 + c0);
                const float4 w3 = *(const float4*)(sW + (k4 * 4 + 3) * 64 + c0);
                FMA4(acc0, a0, w0, w1, w2, w3);
                FMA4(acc1, a1, w0, w1, w2, w3);
            }
        }
        float4 o0, o1;
        o0.x = fmaxf(acc0.x, 0.f); o0.y = fmaxf(acc0.y, 0.f);
        o0.z = fmaxf(acc0.z, 0.f); o0.w = fmaxf(acc0.w, 0.f);
        o1.x = fmaxf(acc1.x, 0.f); o1.y = fmaxf(acc1.y, 0.f);
        o1.z = fmaxf(acc1.z, 0.f); o1.w = fmaxf(acc1.w, 0.f);
        *(float4*)(h1h2 + (r0 + rr * 2 + 0) * 96 + c0) = o0;
        *(float4*)(h1h2 + (r0 + rr * 2 + 1) * 96 + c0) = o1;
    } else if (bid < 768) {
        // ---- h2: 64 rows x 32 cols, K=1024 in 32 tiles of 32, then layer2 in-block.
        float* sA = smem;                 // [64][SPAD]
        float* sW = smem + 64 * SPAD;     // [32][32]
        const long r0 = (long)(bid - 512) * 64;
        const int tr = t & 7, rr = t >> 3;
        const int c0 = tr * 4;
        const int arow0 = t >> 3,        aseg = t & 7;
        const int arow1 = 32 + (t >> 3);
        const float* aSrc0 = mean + (r0 + arow0) * P + aseg * 4;
        const float* aSrc1 = mean + (r0 + arow1) * P + aseg * 4;

        float4 aR0 = *(const float4*)(aSrc0);
        float4 aR1 = *(const float4*)(aSrc1);
        float4 wR  = *(const float4*)(pol_w1 + t * 4);
        float4 acc0 = {0.f,0.f,0.f,0.f}, acc1 = {0.f,0.f,0.f,0.f};

        for (int kt = 0; kt < 32; ++kt) {
            __syncthreads();
            *(float4*)(sA + arow0 * SPAD + aseg * 4) = aR0;
            *(float4*)(sA + arow1 * SPAD + aseg * 4) = aR1;
            *(float4*)(sW + t * 4) = wR;
            __syncthreads();
            if (kt < 31) {
                aR0 = *(const float4*)(aSrc0 + (kt + 1) * 32);
                aR1 = *(const float4*)(aSrc1 + (kt + 1) * 32);
                wR  = *(const float4*)(pol_w1 + (kt + 1) * 1024 + t * 4);
            }
            #pragma unroll
            for (int k4 = 0; k4 < 8; ++k4) {
                const float4 a0 = *(const float4*)(sA + (rr * 2 + 0) * SPAD + k4 * 4);
                const float4 a1 = *(const float4*)(sA + (rr * 2 + 1) * SPAD + k4 * 4);
                const float4 w0 = *(const float4*)(sW + (k4 * 4 + 0) * 32 + c0);
                const float4 w1 = *(const float4*)(sW + (k4 * 4 + 1) * 32 + c0);
                const float4 w2 = *(const float4*)(sW + (k4 * 4 + 2) * 32 + c0);
                const float4 w3 = *(const float4*)(sW + (k4 * 4 + 3) * 32 + c0);
                FMA4(acc0, a0, w0, w1, w2, w3);
                FMA4(acc1, a1, w0, w1, w2, w3);
            }
        }
        __syncthreads();
        {
            const float4 b1 = *(const float4*)(pol_b1 + c0);
            float4 t10, t11;
            t10.x = fmaxf(acc0.x + b1.x, 0.f); t10.y = fmaxf(acc0.y + b1.y, 0.f);
            t10.z = fmaxf(acc0.z + b1.z, 0.f); t10.w = fmaxf(acc0.w + b1.w, 0.f);
            t11.x = fmaxf(acc1.x + b1.x, 0.f); t11.y = fmaxf(acc1.y + b1.y, 0.f);
            t11.z = fmaxf(acc1.z + b1.z, 0.f); t11.w = fmaxf(acc1.w + b1.w, 0.f);
            *(float4*)(sA + (rr * 2 + 0) * SPAD + c0) = t10;
            *(float4*)(sA + (rr * 2 + 1) * SPAD + c0) = t11;
        }
        *(float4*)(sW + t * 4) = *(const float4*)(pol_w2 + t * 4);
        __syncthreads();

        float4 d0 = {0.f,0.f,0.f,0.f}, d1 = {0.f,0.f,0.f,0.f};
        #pragma unroll
        for (int k4 = 0; k4 < 8; ++k4) {
            const float4 a0 = *(const float4*)(sA + (rr * 2 + 0) * SPAD + k4 * 4);
            const float4 a1 = *(const float4*)(sA + (rr * 2 + 1) * SPAD + k4 * 4);
            const float4 w0 = *(const float4*)(sW + (k4 * 4 + 0) * 32 + c0);
            const float4 w1 = *(const float4*)(sW + (k4 * 4 + 1) * 32 + c0);
            const float4 w2 = *(const float4*)(sW + (k4 * 4 + 2) * 32 + c0);
            const float4 w3 = *(const float4*)(sW + (k4 * 4 + 3) * 32 + c0);
            FMA4(d0, a0, w0, w1, w2, w3);
            FMA4(d1, a1, w0, w1, w2, w3);
        }
        const float4 b2 = *(const float4*)(pol_b2 + c0);
        float4 o0, o1;
        o0.x = fmaxf(d0.x + b2.x, 0.f); o0.y = fmaxf(d0.y + b2.y, 0.f);
        o0.z = fmaxf(d0.z + b2.z, 0.f); o0.w = fmaxf(d0.w + b2.w, 0.f);
        o1.x = fmaxf(d1.x + b2.x, 0.f); o1.y = fmaxf(d1.y + b2.y, 0.f);
        o1.z = fmaxf(d1.z + b2.z, 0.f); o1.w = fmaxf(d1.w + b2.w, 0.f);
        *(float4*)(h1h2 + (r0 + rr * 2 + 0) * 96 + 64 + c0) = o0;
        *(float4*)(h1h2 + (r0 + rr * 2 + 1) * 96 + 64 + c0) = o1;
    } else if (bid < 1600) {
        // ---- fused-weight precompute: pid -> (j-chunk, row-group, k-chunk of 64)
        const int pid = bid - 768;          // [0, 832)
        const int jc = pid & 3;
        const int rest = pid >> 2;          // [0, 208)
        const int by = rest % 13;
        const int kz = rest / 13;           // [0, 16)
        const int j = jc * 256 + t;

        const float* wsrc; int nr, kbase, outbase;
        if (by < 8)       { wsrc = enc_w2 + by * 8 * 1024;        nr = 8; kbase = 0;    outbase = by * 8; }
        else if (by < 12) { wsrc = pol_w3 + (by - 8) * 8 * 1024;  nr = 8; kbase = 1024; outbase = 64 + (by - 8) * 8; }
        else              { wsrc = pol_b3;                        nr = 1; kbase = 1024; outbase = 96; }

        float* s_w = smem;   // [8][64]
        for (int i = t; i < nr * 64; i += 256)
            s_w[i] = wsrc[(i >> 6) * 1024 + kz * 64 + (i & 63)];
        __syncthreads();

        float acc[8];
        #pragma unroll
        for (int r = 0; r < 8; ++r) acc[r] = 0.f;
        const float* cw = comb_w + ((size_t)kbase + kz * 64) * 1024 + j;
        #pragma unroll 4
        for (int k = 0; k < 64; ++k) {
            const float c = cw[(size_t)k * 1024];
            #pragma unroll
            for (int r = 0; r < 8; ++r) acc[r] = fmaf(s_w[r * 64 + k], c, acc[r]);
        }
        if (by == 12) {
            atomicAdd(&fused[96 * 1024 + j], acc[0] + (kz == 0 ? comb_b[j] : 0.f));
        } else {
            #pragma unroll
            for (int r = 0; r < 8; ++r) atomicAdd(&fused[(outbase + r) * 1024 + j], acc[r]);
        }
    } else {
        // ---- constant fill: logprob (atomic base) and entropy
        const int idx = (bid - 1600) * 256 + t;   // 64 blocks * 256 = 16384
        out_logprob[idx] = 592.8218660580586f;
        out_entropy[idx] = -80.82186605805855f;
    }
}

// ---------------------------------------------------------------------------
// logits + epilogue, LDS-w edition. Grid 2048 = 256 row-blocks x 8 j-blocks.
// Block = 64 rows x 128 cols; wave w owns rows [16w,16w+16); thread = 16 rows
// x 2 cols (acc[16] float2). fused j-slice (97x128 = 49.7KB) staged to LDS
// once -> per-lane ds_read_b64 (1 per 32 FMA-cyc). h via s_load (wave-uniform
// row base forced with readfirstlane), 4-row chunks. 3 blocks/CU by LDS.
// ---------------------------------------------------------------------------
__global__ __launch_bounds__(256) void logits_ep(
    const float* __restrict__ h1h2,    // [N][96]
    const float* __restrict__ fused,   // [97][1024]
    const float* __restrict__ eps,     // [N][1024]
    float* __restrict__ out_sample,    // [N][1024]
    float* __restrict__ out_logprob)   // [N] (pre-filled with const)
{
    __shared__ __attribute__((aligned(16))) float wlds[97 * 128];  // 49.7 KB
    const int t = threadIdx.x;
    const int jb = blockIdx.x & 7;
    const long r0 = (long)(blockIdx.x >> 3) * 64;
    const int l = t & 63;
    const int rgu = __builtin_amdgcn_readfirstlane(t >> 6);  // wave id -> SGPR

    // ---- stage fused[*][jb*128 .. +128) -> LDS (coalesced f4, linear dst)
    {
        const float* src = fused + jb * 128;
        for (int i = t; i < 97 * 32; i += 256) {
            const int k = i >> 5, c4 = (i & 31) * 4;
            *(float4*)(wlds + k * 128 + c4) = *(const float4*)(src + (size_t)k * 1024 + c4);
        }
    }
    __syncthreads();

    const float2* wl2 = (const float2*)wlds;         // [97][64] float2
    const int myrow0 = (int)r0 + rgu * 16;           // wave-uniform
    const float* hB = h1h2 + (size_t)myrow0 * 96;    // uniform base -> s_load

    float2 acc[16];
    {
        const float2 b = wl2[96 * 64 + l];           // bias row
        #pragma unroll
        for (int r = 0; r < 16; ++r) acc[r] = b;
    }

    #pragma unroll
    for (int k4 = 0; k4 < 24; ++k4) {
        const float2 w0 = wl2[(k4 * 4 + 0) * 64 + l];
        const float2 w1 = wl2[(k4 * 4 + 1) * 64 + l];
        const float2 w2 = wl2[(k4 * 4 + 2) * 64 + l];
        const float2 w3 = wl2[(k4 * 4 + 3) * 64 + l];
        #pragma unroll
        for (int rc = 0; rc < 4; ++rc) {
            #pragma unroll
            for (int q = 0; q < 4; ++q) {
                const int r = rc * 4 + q;
                // wave-uniform address -> s_load_dwordx4
                const float4 h = *(const float4*)(hB + r * 96 + k4 * 4);
                acc[r].x = fmaf(h.x, w0.x, acc[r].x);
                acc[r].y = fmaf(h.x, w0.y, acc[r].y);
                acc[r].x = fmaf(h.y, w1.x, acc[r].x);
                acc[r].y = fmaf(h.y, w1.y, acc[r].y);
                acc[r].x = fmaf(h.z, w2.x, acc[r].x);
                acc[r].y = fmaf(h.z, w2.y, acc[r].y);
                acc[r].x = fmaf(h.w, w3.x, acc[r].x);
                acc[r].y = fmaf(h.w, w3.y, acc[r].y);
            }
        }
    }

    // ---- epilogue: sigmoid, sample, per-row logprob partial (this wave owns rows)
    const float* ep = eps + (size_t)myrow0 * P + jb * 128 + l * 2;
    float* sp = out_sample + (size_t)myrow0 * P + jb * 128 + l * 2;
    float sq[16];
    #pragma unroll
    for (int r = 0; r < 16; ++r) {
        const float m0 = 1.f / (1.f + __expf(-acc[r].x));
        const float m1 = 1.f / (1.f + __expf(-acc[r].y));
        const float2 e = *(const float2*)(ep + (size_t)r * P);
        const float s0 = fminf(fmaxf(fmaf(0.22360679774997896f, e.x, m0), 0.f), 1.f);
        const float s1 = fminf(fmaxf(fmaf(0.22360679774997896f, e.y, m1), 0.f), 1.f);
        *(float2*)(sp + (size_t)r * P) = make_float2(s0, s1);
        const float d0 = s0 - m0, d1 = s1 - m1;
        sq[r] = fmaf(d0, d0, d1 * d1);
    }
    #pragma unroll
    for (int r = 0; r < 16; ++r) {
        float v = sq[r];
        v += __shfl_xor(v, 1);
        v += __shfl_xor(v, 2);
        v += __shfl_xor(v, 4);
        v += __shfl_xor(v, 8);
        v += __shfl_xor(v, 16);
        v += __shfl_xor(v, 32);
        if (l == 0) atomicAdd(&out_logprob[myrow0 + r], -10.f * v);
    }
}

extern "C" void kernel_launch(void* const* d_in, const int* in_sizes, int n_in,
                              void* d_out, int out_size, void* d_ws, size_t ws_size,
                              hipStream_t stream) {
    const float* encoding = (const float*)d_in[0];
    const float* mean     = (const float*)d_in[1];
    const float* enc_w1   = (const float*)d_in[2];
    const float* enc_w2   = (const float*)d_in[3];
    const float* pol_w1   = (const float*)d_in[4];
    const float* pol_b1   = (const float*)d_in[5];
    const float* pol_w2   = (const float*)d_in[6];
    const float* pol_b2   = (const float*)d_in[7];
    const float* pol_w3   = (const float*)d_in[8];
    const float* pol_b3   = (const float*)d_in[9];
    const float* comb_w   = (const float*)d_in[10];
    const float* comb_b   = (const float*)d_in[11];
    const float* eps      = (const float*)d_in[12];

    float* fused = (float*)d_ws;                          // 97*1024 floats
    float* h1h2  = fused + 97 * 1024;                     // 16384*96 floats
    float* out_sample  = (float*)d_out;
    float* out_logprob = out_sample + (size_t)N_CLIENTS * P;
    float* out_entropy = out_logprob + N_CLIENTS;

    (void)hipMemsetAsync(fused, 0, 97 * 1024 * sizeof(float), stream);

    stage1<<<1664, 256, 0, stream>>>(encoding, mean, enc_w1, pol_w1, pol_b1,
                                     pol_w2, pol_b2, enc_w2, pol_w3, pol_b3,
                                     comb_w, comb_b, h1h2, fused,
                                     out_logprob, out_entropy);

    logits_ep<<<2048, 256, 0, stream>>>(
        h1h2, fused, eps, out_sample, out_logprob);
}